// Round 13
// baseline (266.802 us; speedup 1.0000x reference)
//
#include <hip/hip_runtime.h>
#include <cstddef>

// B=8, S=1024, HIDDEN=512, NUM_HEAD=8, HEAD_DIM=64
#define SEQ 1024
#define HID 512
#define NH 8
#define HD 64

typedef __attribute__((ext_vector_type(8))) short bf16x8;
typedef __attribute__((ext_vector_type(4))) float f32x4;

__device__ inline unsigned short f2bf(float f) {
  unsigned u = __builtin_bit_cast(unsigned, f);
  return (unsigned short)((u + 0x7fffu + ((u >> 16) & 1u)) >> 16);
}
__device__ inline float bfhi2f(unsigned u) {  // high 16 bits are the bf16
  return __builtin_bit_cast(float, u & 0xffff0000u);
}
__device__ inline float bflo2f(unsigned u) {
  return __builtin_bit_cast(float, u << 16);
}

// ---------------------------------------------------------------------------
// proj_qkv: one launch for Q,K,V projections (identical to R11 best).
//   z=0 (Q): out [B,H,S,D], scaled 1/8; z=1 (K): [B,H,S,D]; z=2 (V): [B,H,D,S]
// Coalesced epilogue via LDS C-tile.
// ---------------------------------------------------------------------------
__global__ __launch_bounds__(256) void proj_qkv(
    const float* __restrict__ x0, const float* __restrict__ x1, const float* __restrict__ x2,
    const float* __restrict__ w0, const float* __restrict__ w1, const float* __restrict__ w2,
    const float* __restrict__ b0, const float* __restrict__ b1, const float* __restrict__ b2,
    unsigned short* __restrict__ o0, unsigned short* __restrict__ o1,
    unsigned short* __restrict__ o2) {
  __shared__ __align__(16) char smem[32768];
  short* As = (short*)smem;
  short* Bs = As + 128 * 64;
  short* Cs = (short*)smem;

  const int z = blockIdx.z;
  const float* X = z == 0 ? x0 : (z == 1 ? x1 : x2);
  const float* W = z == 0 ? w0 : (z == 1 ? w1 : w2);
  const float* bias = z == 0 ? b0 : (z == 1 ? b1 : b2);
  unsigned short* out = z == 0 ? o0 : (z == 1 ? o1 : o2);
  const float scale = z == 0 ? 0.125f : 1.0f;

  const int t = threadIdx.x;
  const int lane = t & 63, wid = t >> 6;
  const int lg = lane >> 4, lr = lane & 15;
  const int wm = (wid >> 1) * 64, wn = (wid & 1) * 64;
  const int m0 = blockIdx.y * 128, n0 = blockIdx.x * 128;

  f32x4 acc[4][4];
  const f32x4 zf = {0.f, 0.f, 0.f, 0.f};
#pragma unroll
  for (int mg = 0; mg < 4; ++mg)
#pragma unroll
    for (int ng = 0; ng < 4; ++ng) acc[mg][ng] = zf;

  for (int k0 = 0; k0 < 512; k0 += 64) {
    __syncthreads();
#pragma unroll
    for (int i = 0; i < 4; ++i) {
      const int gi = t + i * 256;
      const int r = gi >> 3, g = gi & 7;
      const int dst = r * 64 + ((g ^ (r & 7)) * 8);
      {
        const float* src = X + (size_t)(m0 + r) * 512 + k0 + g * 8;
        const float4 a = *reinterpret_cast<const float4*>(src);
        const float4 b2 = *reinterpret_cast<const float4*>(src + 4);
        union { bf16x8 v; unsigned short u[8]; } p;
        p.u[0] = f2bf(a.x);  p.u[1] = f2bf(a.y);  p.u[2] = f2bf(a.z);  p.u[3] = f2bf(a.w);
        p.u[4] = f2bf(b2.x); p.u[5] = f2bf(b2.y); p.u[6] = f2bf(b2.z); p.u[7] = f2bf(b2.w);
        *reinterpret_cast<bf16x8*>(As + dst) = p.v;
      }
      {
        const float* srcw = W + (size_t)(n0 + r) * 512 + k0 + g * 8;
        const float4 wa = *reinterpret_cast<const float4*>(srcw);
        const float4 wb = *reinterpret_cast<const float4*>(srcw + 4);
        union { bf16x8 v; unsigned short u[8]; } q;
        q.u[0] = f2bf(wa.x); q.u[1] = f2bf(wa.y); q.u[2] = f2bf(wa.z); q.u[3] = f2bf(wa.w);
        q.u[4] = f2bf(wb.x); q.u[5] = f2bf(wb.y); q.u[6] = f2bf(wb.z); q.u[7] = f2bf(wb.w);
        *reinterpret_cast<bf16x8*>(Bs + dst) = q.v;
      }
    }
    __syncthreads();

#pragma unroll
    for (int c = 0; c < 2; ++c) {
      bf16x8 af[4], bfr[4];
#pragma unroll
      for (int mg = 0; mg < 4; ++mg) {
        const int r = wm + mg * 16 + lr;
        af[mg] = *reinterpret_cast<const bf16x8*>(As + r * 64 + (((lg + 4 * c) ^ (r & 7)) * 8));
      }
#pragma unroll
      for (int ng = 0; ng < 4; ++ng) {
        const int r = wn + ng * 16 + lr;
        bfr[ng] = *reinterpret_cast<const bf16x8*>(Bs + r * 64 + (((lg + 4 * c) ^ (r & 7)) * 8));
      }
#pragma unroll
      for (int mg = 0; mg < 4; ++mg)
#pragma unroll
        for (int ng = 0; ng < 4; ++ng)
          acc[mg][ng] =
              __builtin_amdgcn_mfma_f32_16x16x32_bf16(af[mg], bfr[ng], acc[mg][ng], 0, 0, 0);
    }
  }

  float bv[4];
#pragma unroll
  for (int ng = 0; ng < 4; ++ng) bv[ng] = bias[n0 + wn + ng * 16 + lr];

  __syncthreads();

  if (z == 2) {
#pragma unroll
    for (int mg = 0; mg < 4; ++mg) {
#pragma unroll
      for (int reg = 0; reg < 4; ++reg) {
        const int mi = wm + mg * 16 + 4 * lg + reg;
#pragma unroll
        for (int ng = 0; ng < 4; ++ng) {
          const int ni = wn + ng * 16 + lr;
          Cs[ni * 128 + (((mi >> 3) ^ (ni & 15)) * 8) + (mi & 7)] =
              f2bf(acc[mg][ng][reg] + bv[ng]);
        }
      }
    }
  } else {
#pragma unroll
    for (int mg = 0; mg < 4; ++mg) {
#pragma unroll
      for (int reg = 0; reg < 4; ++reg) {
        const int mi = wm + mg * 16 + 4 * lg + reg;
#pragma unroll
        for (int ng = 0; ng < 4; ++ng) {
          const int ni = wn + ng * 16 + lr;
          Cs[mi * 128 + ni] = f2bf((acc[mg][ng][reg] + bv[ng]) * scale);
        }
      }
    }
  }
  __syncthreads();

  const int bb = m0 >> 10;
  const int s_base = m0 & 1023;
  if (z == 2) {
#pragma unroll
    for (int rr = 0; rr < 8; ++rr) {
      const int e = t + rr * 256;
      const int dr = e >> 4;
      const int gm = e & 15;
      const bf16x8 v8 =
          *reinterpret_cast<const bf16x8*>(Cs + dr * 128 + ((gm ^ (dr & 15)) * 8));
      const int h = (n0 + dr) >> 6, d = (n0 + dr) & 63;
      *reinterpret_cast<bf16x8*>(
          out + (((size_t)(bb * NH + h)) * HD + d) * SEQ + s_base + gm * 8) = v8;
    }
  } else {
#pragma unroll
    for (int rr = 0; rr < 8; ++rr) {
      const int e = t + rr * 256;
      const int mi = e >> 4;
      const int gc = e & 15;
      const bf16x8 v8 = *reinterpret_cast<const bf16x8*>(Cs + mi * 128 + gc * 8);
      const int n = n0 + gc * 8;
      const int h = n >> 6, d = n & 63;
      *reinterpret_cast<bf16x8*>(
          out + (((size_t)(bb * NH + h)) * SEQ + s_base + mi) * HD + d) = v8;
    }
  }
}

// ---------------------------------------------------------------------------
// proj_out: atted[8192][512] f32 = X(bf16) @ Wm^T + bm (R11/R12 version)
// ---------------------------------------------------------------------------
__global__ __launch_bounds__(256) void proj_out(const unsigned short* __restrict__ Xb,
                                                const float* __restrict__ W,
                                                const float* __restrict__ bias,
                                                float* __restrict__ outv) {
  __shared__ __align__(16) char smem[32768];
  short* As = (short*)smem;
  short* Bs = As + 128 * 64;
  float* Cs = (float*)smem;  // [64][128] f32 overlay

  const int t = threadIdx.x;
  const int lane = t & 63, wid = t >> 6;
  const int lg = lane >> 4, lr = lane & 15;
  const int wm = (wid >> 1) * 64, wn = (wid & 1) * 64;
  const int m0 = blockIdx.y * 128, n0 = blockIdx.x * 128;

  f32x4 acc[4][4];
  const f32x4 zf = {0.f, 0.f, 0.f, 0.f};
#pragma unroll
  for (int mg = 0; mg < 4; ++mg)
#pragma unroll
    for (int ng = 0; ng < 4; ++ng) acc[mg][ng] = zf;

  for (int k0 = 0; k0 < 512; k0 += 64) {
    __syncthreads();
#pragma unroll
    for (int i = 0; i < 4; ++i) {
      const int gi = t + i * 256;
      const int r = gi >> 3, g = gi & 7;
      const int dst = r * 64 + ((g ^ (r & 7)) * 8);
      *reinterpret_cast<bf16x8*>(As + dst) =
          *reinterpret_cast<const bf16x8*>(Xb + (size_t)(m0 + r) * 512 + k0 + g * 8);
      const float* srcw = W + (size_t)(n0 + r) * 512 + k0 + g * 8;
      const float4 wa = *reinterpret_cast<const float4*>(srcw);
      const float4 wb = *reinterpret_cast<const float4*>(srcw + 4);
      union { bf16x8 v; unsigned short u[8]; } q;
      q.u[0] = f2bf(wa.x); q.u[1] = f2bf(wa.y); q.u[2] = f2bf(wa.z); q.u[3] = f2bf(wa.w);
      q.u[4] = f2bf(wb.x); q.u[5] = f2bf(wb.y); q.u[6] = f2bf(wb.z); q.u[7] = f2bf(wb.w);
      *reinterpret_cast<bf16x8*>(Bs + dst) = q.v;
    }
    __syncthreads();

#pragma unroll
    for (int c = 0; c < 2; ++c) {
      bf16x8 af[4], bfr[4];
#pragma unroll
      for (int mg = 0; mg < 4; ++mg) {
        const int r = wm + mg * 16 + lr;
        af[mg] = *reinterpret_cast<const bf16x8*>(As + r * 64 + (((lg + 4 * c) ^ (r & 7)) * 8));
      }
#pragma unroll
      for (int ng = 0; ng < 4; ++ng) {
        const int r = wn + ng * 16 + lr;
        bfr[ng] = *reinterpret_cast<const bf16x8*>(Bs + r * 64 + (((lg + 4 * c) ^ (r & 7)) * 8));
      }
#pragma unroll
      for (int mg = 0; mg < 4; ++mg)
#pragma unroll
        for (int ng = 0; ng < 4; ++ng)
          acc[mg][ng] =
              __builtin_amdgcn_mfma_f32_16x16x32_bf16(af[mg], bfr[ng], acc[mg][ng], 0, 0, 0);
    }
  }

  float bv[4];
#pragma unroll
  for (int ng = 0; ng < 4; ++ng) bv[ng] = bias[n0 + wn + ng * 16 + lr];

  __syncthreads();

#pragma unroll
  for (int half = 0; half < 2; ++half) {
    if ((wid >> 1) == half) {
#pragma unroll
      for (int mg = 0; mg < 4; ++mg) {
#pragma unroll
        for (int reg = 0; reg < 4; ++reg) {
          const int row = mg * 16 + 4 * lg + reg;  // 0..63 local
#pragma unroll
          for (int ng = 0; ng < 4; ++ng)
            Cs[row * 128 + wn + ng * 16 + lr] = acc[mg][ng][reg] + bv[ng];
        }
      }
    }
    __syncthreads();
#pragma unroll
    for (int rr = 0; rr < 8; ++rr) {
      const int g = t + rr * 256;      // 2048 f32x4 granules
      const int row = g >> 5;          // 0..63
      const int gc = g & 31;
      const f32x4 w4 = *reinterpret_cast<const f32x4*>(Cs + row * 128 + gc * 4);
      *reinterpret_cast<f32x4*>(outv + (size_t)(m0 + half * 64 + row) * 512 + n0 + gc * 4) = w4;
    }
    __syncthreads();
  }
}

// ---------------------------------------------------------------------------
// attn_fused: SINGLE-QK with register-held P. K-split: block = (bh, 32 q);
// 2 pairs x 2 waves; pair p owns q0=qt*32+p*16; wave w owns keys [512w,512w+512).
// Phase 1 (barrier-free, R12-verified): QK direct-K, exp, partial rs,
//   P->preg[32] (packed bf16, 64 VGPR) AND ->own LDS for PV, partial PV with
//   direct V^T reads. One barrier merges rs + oacc (partner's LDS region).
// Phase 2: pair-leader writes atted.
// Phase 3: att_map = pure dependency-free store burst from preg * inv.
// NO QK/exp recompute, NO K re-reads, NO store-wait chains.
// ---------------------------------------------------------------------------
__global__ __launch_bounds__(256, 4) void attn_fused(const unsigned short* __restrict__ qh,
                                                     const unsigned short* __restrict__ kh,
                                                     const unsigned short* __restrict__ vhT,
                                                     const unsigned char* __restrict__ mask,
                                                     float* __restrict__ att_map,
                                                     unsigned short* __restrict__ atted) {
  __shared__ short Pw4[4][2048];   // 16 KB per-wave P bounce (w==1 regions reused as f32 oacc buf)
  __shared__ float rsbuf[4][16];

  const int t = threadIdx.x;
  const int lane = t & 63, wid = t >> 6;
  const int lg = lane >> 4, lr = lane & 15;
  const int pair = wid >> 1, w = wid & 1;
  const int qt = blockIdx.x & 31;   // 32 q-tiles of 32 rows
  const int bh = blockIdx.x >> 5;   // 0..63
  const int b = bh >> 3, h = bh & 7;
  const int q0 = qt * 32 + pair * 16;
  const int k0w = w * 512;

  const unsigned short* Qb = qh + ((size_t)bh * SEQ + q0) * HD;
  const unsigned short* Kb = kh + (size_t)bh * SEQ * HD;   // [s][d]
  const unsigned short* Vb = vhT + (size_t)bh * HD * SEQ;  // [d][s]
  const unsigned char* mrow = mask + (size_t)b * SEQ;

  // Q fragments (B-operand: lane lr = q-row; k-granule = lg + 4c). Scaled 1/8.
  bf16x8 qf[2];
#pragma unroll
  for (int c = 0; c < 2; ++c)
    qf[c] = *reinterpret_cast<const bf16x8*>(Qb + (size_t)lr * HD + lg * 8 + 32 * c);

  const f32x4 zf = {0.f, 0.f, 0.f, 0.f};
  f32x4 oacc[4] = {zf, zf, zf, zf};
  float rs = 0.f;
  short* Pw = Pw4[wid];
  uint2 preg[32];  // lane's P slice: 128 bf16 (rows lr; keys k0w..k0w+511)

  // -------------------- Phase 1: partial compute, barrier-free ------------
#pragma unroll
  for (int kt = 0; kt < 4; ++kt) {
    const int kb = k0w + kt * 128;
#pragma unroll
    for (int cg = 0; cg < 8; ++cg) {
      const int r = kb + cg * 16 + lr;  // key row (A-operand row = lr)
      f32x4 s = zf;
#pragma unroll
      for (int c = 0; c < 2; ++c) {
        const bf16x8 kf =
            *reinterpret_cast<const bf16x8*>(Kb + (size_t)r * HD + (lg + 4 * c) * 8);
        s = __builtin_amdgcn_mfma_f32_16x16x32_bf16(kf, qf[c], s, 0, 0, 0);
      }
      const uchar4 m4 = *reinterpret_cast<const uchar4*>(mrow + kb + cg * 16 + 4 * lg);
      const float p0 = __expf(s[0] + (m4.x ? -10000.f : 0.f));
      const float p1 = __expf(s[1] + (m4.y ? -10000.f : 0.f));
      const float p2 = __expf(s[2] + (m4.z ? -10000.f : 0.f));
      const float p3 = __expf(s[3] + (m4.w ? -10000.f : 0.f));
      rs += (p0 + p1) + (p2 + p3);
      uint2 pr;
      pr.x = (unsigned)f2bf(p0) | ((unsigned)f2bf(p1) << 16);
      pr.y = (unsigned)f2bf(p2) | ((unsigned)f2bf(p3) << 16);
      preg[kt * 8 + cg] = pr;
      const int gk = 2 * cg + (lg >> 1);
      *reinterpret_cast<uint2*>(Pw + lr * 128 + ((gk ^ (lr & 7)) * 8) + (lg & 1) * 4) = pr;
    }

    // partial PV: O[16 q][64 d] += P[16][128] * V[128][64], V direct global
#pragma unroll
    for (int c = 0; c < 4; ++c) {
      const bf16x8 pa =
          *reinterpret_cast<const bf16x8*>(Pw + lr * 128 + (((lg + 4 * c) ^ (lr & 7)) * 8));
#pragma unroll
      for (int ng = 0; ng < 4; ++ng) {
        const int d = ng * 16 + lr;
        const bf16x8 vf = *reinterpret_cast<const bf16x8*>(
            Vb + (size_t)d * SEQ + kb + (4 * c + lg) * 8);
        oacc[ng] = __builtin_amdgcn_mfma_f32_16x16x32_bf16(pa, vf, oacc[ng], 0, 0, 0);
      }
    }
  }

  // intra-wave rowsum reduce (across lg groups)
  rs += __shfl_xor(rs, 16);
  rs += __shfl_xor(rs, 32);
  if (lane < 16) rsbuf[wid][lane] = rs;
  if (w == 1) {  // export partial oacc via own (now-free) P region as f32
    float* ob = (float*)Pw;
#pragma unroll
    for (int ng = 0; ng < 4; ++ng)
#pragma unroll
      for (int reg = 0; reg < 4; ++reg)
        ob[(4 * lg + reg) * 64 + ng * 16 + lr] = oacc[ng][reg];
  }
  __syncthreads();

  const float inv = 1.f / (rsbuf[pair * 2][lr] + rsbuf[pair * 2 + 1][lr]);

  // -------------------- Phase 2: pair-leader writes atted -----------------
  if (w == 0) {
    const float* ob = (const float*)(Pw4[wid + 1]);
    float invq[4];
#pragma unroll
    for (int reg = 0; reg < 4; ++reg) invq[reg] = __shfl(inv, 4 * lg + reg);
#pragma unroll
    for (int ng = 0; ng < 4; ++ng) {
#pragma unroll
      for (int reg = 0; reg < 4; ++reg) {
        const int q = q0 + 4 * lg + reg;
        const int d = ng * 16 + lr;
        const float o = oacc[ng][reg] + ob[(4 * lg + reg) * 64 + d];
        atted[((size_t)b * SEQ + q) * HID + h * HD + d] = f2bf(o * invq[reg]);
      }
    }
  }

  // -------------------- Phase 3: att_map burst from registers -------------
  // Pure stores, nothing depends on them. Row q0+lr, keys k0w + cg*16 + 4lg.
  float* arow = att_map + ((size_t)bh * SEQ + q0 + lr) * SEQ + k0w + 4 * lg;
#pragma unroll
  for (int cg = 0; cg < 32; ++cg) {
    const uint2 pr = preg[cg];
    f32x4 wv;
    wv.x = bflo2f(pr.x) * inv;
    wv.y = bfhi2f(pr.x) * inv;
    wv.z = bflo2f(pr.y) * inv;
    wv.w = bfhi2f(pr.y) * inv;
    __builtin_nontemporal_store(wv, reinterpret_cast<f32x4*>(arow + cg * 16));
  }
}

// ---------------------------------------------------------------------------
extern "C" void kernel_launch(void* const* d_in, const int* in_sizes, int n_in,
                              void* d_out, int out_size, void* d_ws, size_t ws_size,
                              hipStream_t stream) {
  const float* v = (const float*)d_in[0];
  const float* k = (const float*)d_in[1];
  const float* q = (const float*)d_in[2];
  const unsigned char* mask = (const unsigned char*)d_in[3];
  const float* Wv = (const float*)d_in[4];
  const float* bv = (const float*)d_in[5];
  const float* Wk = (const float*)d_in[6];
  const float* bk = (const float*)d_in[7];
  const float* Wq = (const float*)d_in[8];
  const float* bq = (const float*)d_in[9];
  const float* Wm = (const float*)d_in[10];
  const float* bm = (const float*)d_in[11];

  float* out_atted = (float*)d_out;                    // [8,1024,512] f32
  float* out_att = out_atted + (size_t)8 * SEQ * HID;  // [8,8,1024,1024] f32

  const size_t TN = (size_t)8 * SEQ * HID;
  unsigned short* qh = (unsigned short*)d_ws;  // bf16 [B,H,S,D]
  unsigned short* kh = qh + TN;
  unsigned short* vhT = kh + TN;               // bf16 [B,H,D,S]
  unsigned short* aw = vhT + TN;               // bf16 [B,S,H*D]

  proj_qkv<<<dim3(4, 64, 3), 256, 0, stream>>>(q, k, v, Wq, Wk, Wv, bq, bk, bv, qh, kh, vhT);

  attn_fused<<<dim3(2048), 256, 0, stream>>>(qh, kh, vhT, mask, out_att, aw);

  proj_out<<<dim3(4, 64), 256, 0, stream>>>(aw, Wm, bm, out_atted);
}

// Round 14
// 256.775 us; speedup vs baseline: 1.0390x; 1.0390x over previous
//
#include <hip/hip_runtime.h>
#include <cstddef>

// B=8, S=1024, HIDDEN=512, NUM_HEAD=8, HEAD_DIM=64
#define SEQ 1024
#define HID 512
#define NH 8
#define HD 64

typedef __attribute__((ext_vector_type(8))) short bf16x8;
typedef __attribute__((ext_vector_type(4))) float f32x4;

__device__ inline unsigned short f2bf(float f) {
  unsigned u = __builtin_bit_cast(unsigned, f);
  return (unsigned short)((u + 0x7fffu + ((u >> 16) & 1u)) >> 16);
}
__device__ inline float bfhi2f(unsigned u) {  // high 16 bits are the bf16
  return __builtin_bit_cast(float, u & 0xffff0000u);
}
__device__ inline float bflo2f(unsigned u) {
  return __builtin_bit_cast(float, u << 16);
}

// ---------------------------------------------------------------------------
// proj_qkv: one launch for Q,K,V projections (identical to R11 best).
//   z=0 (Q): out [B,H,S,D], scaled 1/8; z=1 (K): [B,H,S,D]; z=2 (V): [B,H,D,S]
// Coalesced epilogue via LDS C-tile.
// ---------------------------------------------------------------------------
__global__ __launch_bounds__(256) void proj_qkv(
    const float* __restrict__ x0, const float* __restrict__ x1, const float* __restrict__ x2,
    const float* __restrict__ w0, const float* __restrict__ w1, const float* __restrict__ w2,
    const float* __restrict__ b0, const float* __restrict__ b1, const float* __restrict__ b2,
    unsigned short* __restrict__ o0, unsigned short* __restrict__ o1,
    unsigned short* __restrict__ o2) {
  __shared__ __align__(16) char smem[32768];
  short* As = (short*)smem;
  short* Bs = As + 128 * 64;
  short* Cs = (short*)smem;

  const int z = blockIdx.z;
  const float* X = z == 0 ? x0 : (z == 1 ? x1 : x2);
  const float* W = z == 0 ? w0 : (z == 1 ? w1 : w2);
  const float* bias = z == 0 ? b0 : (z == 1 ? b1 : b2);
  unsigned short* out = z == 0 ? o0 : (z == 1 ? o1 : o2);
  const float scale = z == 0 ? 0.125f : 1.0f;

  const int t = threadIdx.x;
  const int lane = t & 63, wid = t >> 6;
  const int lg = lane >> 4, lr = lane & 15;
  const int wm = (wid >> 1) * 64, wn = (wid & 1) * 64;
  const int m0 = blockIdx.y * 128, n0 = blockIdx.x * 128;

  f32x4 acc[4][4];
  const f32x4 zf = {0.f, 0.f, 0.f, 0.f};
#pragma unroll
  for (int mg = 0; mg < 4; ++mg)
#pragma unroll
    for (int ng = 0; ng < 4; ++ng) acc[mg][ng] = zf;

  for (int k0 = 0; k0 < 512; k0 += 64) {
    __syncthreads();
#pragma unroll
    for (int i = 0; i < 4; ++i) {
      const int gi = t + i * 256;
      const int r = gi >> 3, g = gi & 7;
      const int dst = r * 64 + ((g ^ (r & 7)) * 8);
      {
        const float* src = X + (size_t)(m0 + r) * 512 + k0 + g * 8;
        const float4 a = *reinterpret_cast<const float4*>(src);
        const float4 b2 = *reinterpret_cast<const float4*>(src + 4);
        union { bf16x8 v; unsigned short u[8]; } p;
        p.u[0] = f2bf(a.x);  p.u[1] = f2bf(a.y);  p.u[2] = f2bf(a.z);  p.u[3] = f2bf(a.w);
        p.u[4] = f2bf(b2.x); p.u[5] = f2bf(b2.y); p.u[6] = f2bf(b2.z); p.u[7] = f2bf(b2.w);
        *reinterpret_cast<bf16x8*>(As + dst) = p.v;
      }
      {
        const float* srcw = W + (size_t)(n0 + r) * 512 + k0 + g * 8;
        const float4 wa = *reinterpret_cast<const float4*>(srcw);
        const float4 wb = *reinterpret_cast<const float4*>(srcw + 4);
        union { bf16x8 v; unsigned short u[8]; } q;
        q.u[0] = f2bf(wa.x); q.u[1] = f2bf(wa.y); q.u[2] = f2bf(wa.z); q.u[3] = f2bf(wa.w);
        q.u[4] = f2bf(wb.x); q.u[5] = f2bf(wb.y); q.u[6] = f2bf(wb.z); q.u[7] = f2bf(wb.w);
        *reinterpret_cast<bf16x8*>(Bs + dst) = q.v;
      }
    }
    __syncthreads();

#pragma unroll
    for (int c = 0; c < 2; ++c) {
      bf16x8 af[4], bfr[4];
#pragma unroll
      for (int mg = 0; mg < 4; ++mg) {
        const int r = wm + mg * 16 + lr;
        af[mg] = *reinterpret_cast<const bf16x8*>(As + r * 64 + (((lg + 4 * c) ^ (r & 7)) * 8));
      }
#pragma unroll
      for (int ng = 0; ng < 4; ++ng) {
        const int r = wn + ng * 16 + lr;
        bfr[ng] = *reinterpret_cast<const bf16x8*>(Bs + r * 64 + (((lg + 4 * c) ^ (r & 7)) * 8));
      }
#pragma unroll
      for (int mg = 0; mg < 4; ++mg)
#pragma unroll
        for (int ng = 0; ng < 4; ++ng)
          acc[mg][ng] =
              __builtin_amdgcn_mfma_f32_16x16x32_bf16(af[mg], bfr[ng], acc[mg][ng], 0, 0, 0);
    }
  }

  float bv[4];
#pragma unroll
  for (int ng = 0; ng < 4; ++ng) bv[ng] = bias[n0 + wn + ng * 16 + lr];

  __syncthreads();

  if (z == 2) {
#pragma unroll
    for (int mg = 0; mg < 4; ++mg) {
#pragma unroll
      for (int reg = 0; reg < 4; ++reg) {
        const int mi = wm + mg * 16 + 4 * lg + reg;
#pragma unroll
        for (int ng = 0; ng < 4; ++ng) {
          const int ni = wn + ng * 16 + lr;
          Cs[ni * 128 + (((mi >> 3) ^ (ni & 15)) * 8) + (mi & 7)] =
              f2bf(acc[mg][ng][reg] + bv[ng]);
        }
      }
    }
  } else {
#pragma unroll
    for (int mg = 0; mg < 4; ++mg) {
#pragma unroll
      for (int reg = 0; reg < 4; ++reg) {
        const int mi = wm + mg * 16 + 4 * lg + reg;
#pragma unroll
        for (int ng = 0; ng < 4; ++ng) {
          const int ni = wn + ng * 16 + lr;
          Cs[mi * 128 + ni] = f2bf((acc[mg][ng][reg] + bv[ng]) * scale);
        }
      }
    }
  }
  __syncthreads();

  const int bb = m0 >> 10;
  const int s_base = m0 & 1023;
  if (z == 2) {
#pragma unroll
    for (int rr = 0; rr < 8; ++rr) {
      const int e = t + rr * 256;
      const int dr = e >> 4;
      const int gm = e & 15;
      const bf16x8 v8 =
          *reinterpret_cast<const bf16x8*>(Cs + dr * 128 + ((gm ^ (dr & 15)) * 8));
      const int h = (n0 + dr) >> 6, d = (n0 + dr) & 63;
      *reinterpret_cast<bf16x8*>(
          out + (((size_t)(bb * NH + h)) * HD + d) * SEQ + s_base + gm * 8) = v8;
    }
  } else {
#pragma unroll
    for (int rr = 0; rr < 8; ++rr) {
      const int e = t + rr * 256;
      const int mi = e >> 4;
      const int gc = e & 15;
      const bf16x8 v8 = *reinterpret_cast<const bf16x8*>(Cs + mi * 128 + gc * 8);
      const int n = n0 + gc * 8;
      const int h = n >> 6, d = n & 63;
      *reinterpret_cast<bf16x8*>(
          out + (((size_t)(bb * NH + h)) * SEQ + s_base + mi) * HD + d) = v8;
    }
  }
}

// ---------------------------------------------------------------------------
// proj_out: atted[8192][512] f32 = X(bf16) @ Wm^T + bm (R11/R12 version)
// ---------------------------------------------------------------------------
__global__ __launch_bounds__(256) void proj_out(const unsigned short* __restrict__ Xb,
                                                const float* __restrict__ W,
                                                const float* __restrict__ bias,
                                                float* __restrict__ outv) {
  __shared__ __align__(16) char smem[32768];
  short* As = (short*)smem;
  short* Bs = As + 128 * 64;
  float* Cs = (float*)smem;  // [64][128] f32 overlay

  const int t = threadIdx.x;
  const int lane = t & 63, wid = t >> 6;
  const int lg = lane >> 4, lr = lane & 15;
  const int wm = (wid >> 1) * 64, wn = (wid & 1) * 64;
  const int m0 = blockIdx.y * 128, n0 = blockIdx.x * 128;

  f32x4 acc[4][4];
  const f32x4 zf = {0.f, 0.f, 0.f, 0.f};
#pragma unroll
  for (int mg = 0; mg < 4; ++mg)
#pragma unroll
    for (int ng = 0; ng < 4; ++ng) acc[mg][ng] = zf;

  for (int k0 = 0; k0 < 512; k0 += 64) {
    __syncthreads();
#pragma unroll
    for (int i = 0; i < 4; ++i) {
      const int gi = t + i * 256;
      const int r = gi >> 3, g = gi & 7;
      const int dst = r * 64 + ((g ^ (r & 7)) * 8);
      *reinterpret_cast<bf16x8*>(As + dst) =
          *reinterpret_cast<const bf16x8*>(Xb + (size_t)(m0 + r) * 512 + k0 + g * 8);
      const float* srcw = W + (size_t)(n0 + r) * 512 + k0 + g * 8;
      const float4 wa = *reinterpret_cast<const float4*>(srcw);
      const float4 wb = *reinterpret_cast<const float4*>(srcw + 4);
      union { bf16x8 v; unsigned short u[8]; } q;
      q.u[0] = f2bf(wa.x); q.u[1] = f2bf(wa.y); q.u[2] = f2bf(wa.z); q.u[3] = f2bf(wa.w);
      q.u[4] = f2bf(wb.x); q.u[5] = f2bf(wb.y); q.u[6] = f2bf(wb.z); q.u[7] = f2bf(wb.w);
      *reinterpret_cast<bf16x8*>(Bs + dst) = q.v;
    }
    __syncthreads();

#pragma unroll
    for (int c = 0; c < 2; ++c) {
      bf16x8 af[4], bfr[4];
#pragma unroll
      for (int mg = 0; mg < 4; ++mg) {
        const int r = wm + mg * 16 + lr;
        af[mg] = *reinterpret_cast<const bf16x8*>(As + r * 64 + (((lg + 4 * c) ^ (r & 7)) * 8));
      }
#pragma unroll
      for (int ng = 0; ng < 4; ++ng) {
        const int r = wn + ng * 16 + lr;
        bfr[ng] = *reinterpret_cast<const bf16x8*>(Bs + r * 64 + (((lg + 4 * c) ^ (r & 7)) * 8));
      }
#pragma unroll
      for (int mg = 0; mg < 4; ++mg)
#pragma unroll
        for (int ng = 0; ng < 4; ++ng)
          acc[mg][ng] =
              __builtin_amdgcn_mfma_f32_16x16x32_bf16(af[mg], bfr[ng], acc[mg][ng], 0, 0, 0);
    }
  }

  float bv[4];
#pragma unroll
  for (int ng = 0; ng < 4; ++ng) bv[ng] = bias[n0 + wn + ng * 16 + lr];

  __syncthreads();

#pragma unroll
  for (int half = 0; half < 2; ++half) {
    if ((wid >> 1) == half) {
#pragma unroll
      for (int mg = 0; mg < 4; ++mg) {
#pragma unroll
        for (int reg = 0; reg < 4; ++reg) {
          const int row = mg * 16 + 4 * lg + reg;  // 0..63 local
#pragma unroll
          for (int ng = 0; ng < 4; ++ng)
            Cs[row * 128 + wn + ng * 16 + lr] = acc[mg][ng][reg] + bv[ng];
        }
      }
    }
    __syncthreads();
#pragma unroll
    for (int rr = 0; rr < 8; ++rr) {
      const int g = t + rr * 256;      // 2048 f32x4 granules
      const int row = g >> 5;          // 0..63
      const int gc = g & 31;
      const f32x4 w4 = *reinterpret_cast<const f32x4*>(Cs + row * 128 + gc * 4);
      *reinterpret_cast<f32x4*>(outv + (size_t)(m0 + half * 64 + row) * 512 + n0 + gc * 4) = w4;
    }
    __syncthreads();
  }
}

// ---------------------------------------------------------------------------
// attn_fused: SINGLE-QK with register-held P (R13 structure) with two fixes:
//  (a) att_map burst uses PLAIN stores (L2 write-combining merges the two
//      adjacent 64B halves per 128B line -> no partial-line amplification);
//  (b) __launch_bounds__(256,2): 256-VGPR cap so preg[32] provably stays in
//      registers (no scratch spill traffic).
// K-split: block = (bh, 32 q); 2 pairs x 2 waves; wave w owns keys
// [512w, 512w+512). Phase 1 barrier-free; one merge barrier; atted; burst.
// ---------------------------------------------------------------------------
__global__ __launch_bounds__(256, 2) void attn_fused(const unsigned short* __restrict__ qh,
                                                     const unsigned short* __restrict__ kh,
                                                     const unsigned short* __restrict__ vhT,
                                                     const unsigned char* __restrict__ mask,
                                                     float* __restrict__ att_map,
                                                     unsigned short* __restrict__ atted) {
  __shared__ short Pw4[4][2048];   // 16 KB per-wave P bounce (w==1 regions reused as f32 oacc buf)
  __shared__ float rsbuf[4][16];

  const int t = threadIdx.x;
  const int lane = t & 63, wid = t >> 6;
  const int lg = lane >> 4, lr = lane & 15;
  const int pair = wid >> 1, w = wid & 1;
  const int qt = blockIdx.x & 31;   // 32 q-tiles of 32 rows
  const int bh = blockIdx.x >> 5;   // 0..63
  const int b = bh >> 3, h = bh & 7;
  const int q0 = qt * 32 + pair * 16;
  const int k0w = w * 512;

  const unsigned short* Qb = qh + ((size_t)bh * SEQ + q0) * HD;
  const unsigned short* Kb = kh + (size_t)bh * SEQ * HD;   // [s][d]
  const unsigned short* Vb = vhT + (size_t)bh * HD * SEQ;  // [d][s]
  const unsigned char* mrow = mask + (size_t)b * SEQ;

  // Q fragments (B-operand: lane lr = q-row; k-granule = lg + 4c). Scaled 1/8.
  bf16x8 qf[2];
#pragma unroll
  for (int c = 0; c < 2; ++c)
    qf[c] = *reinterpret_cast<const bf16x8*>(Qb + (size_t)lr * HD + lg * 8 + 32 * c);

  const f32x4 zf = {0.f, 0.f, 0.f, 0.f};
  f32x4 oacc[4] = {zf, zf, zf, zf};
  float rs = 0.f;
  short* Pw = Pw4[wid];
  uint2 preg[32];  // lane's P slice: 128 bf16 (rows lr; keys k0w..k0w+511)

  // -------------------- Phase 1: partial compute, barrier-free ------------
#pragma unroll
  for (int kt = 0; kt < 4; ++kt) {
    const int kb = k0w + kt * 128;
#pragma unroll
    for (int cg = 0; cg < 8; ++cg) {
      const int r = kb + cg * 16 + lr;  // key row (A-operand row = lr)
      f32x4 s = zf;
#pragma unroll
      for (int c = 0; c < 2; ++c) {
        const bf16x8 kf =
            *reinterpret_cast<const bf16x8*>(Kb + (size_t)r * HD + (lg + 4 * c) * 8);
        s = __builtin_amdgcn_mfma_f32_16x16x32_bf16(kf, qf[c], s, 0, 0, 0);
      }
      const uchar4 m4 = *reinterpret_cast<const uchar4*>(mrow + kb + cg * 16 + 4 * lg);
      const float p0 = __expf(s[0] + (m4.x ? -10000.f : 0.f));
      const float p1 = __expf(s[1] + (m4.y ? -10000.f : 0.f));
      const float p2 = __expf(s[2] + (m4.z ? -10000.f : 0.f));
      const float p3 = __expf(s[3] + (m4.w ? -10000.f : 0.f));
      rs += (p0 + p1) + (p2 + p3);
      uint2 pr;
      pr.x = (unsigned)f2bf(p0) | ((unsigned)f2bf(p1) << 16);
      pr.y = (unsigned)f2bf(p2) | ((unsigned)f2bf(p3) << 16);
      preg[kt * 8 + cg] = pr;
      const int gk = 2 * cg + (lg >> 1);
      *reinterpret_cast<uint2*>(Pw + lr * 128 + ((gk ^ (lr & 7)) * 8) + (lg & 1) * 4) = pr;
    }

    // partial PV: O[16 q][64 d] += P[16][128] * V[128][64], V direct global
#pragma unroll
    for (int c = 0; c < 4; ++c) {
      const bf16x8 pa =
          *reinterpret_cast<const bf16x8*>(Pw + lr * 128 + (((lg + 4 * c) ^ (lr & 7)) * 8));
#pragma unroll
      for (int ng = 0; ng < 4; ++ng) {
        const int d = ng * 16 + lr;
        const bf16x8 vf = *reinterpret_cast<const bf16x8*>(
            Vb + (size_t)d * SEQ + kb + (4 * c + lg) * 8);
        oacc[ng] = __builtin_amdgcn_mfma_f32_16x16x32_bf16(pa, vf, oacc[ng], 0, 0, 0);
      }
    }
  }

  // intra-wave rowsum reduce (across lg groups)
  rs += __shfl_xor(rs, 16);
  rs += __shfl_xor(rs, 32);
  if (lane < 16) rsbuf[wid][lane] = rs;
  if (w == 1) {  // export partial oacc via own (now-free) P region as f32
    float* ob = (float*)Pw;
#pragma unroll
    for (int ng = 0; ng < 4; ++ng)
#pragma unroll
      for (int reg = 0; reg < 4; ++reg)
        ob[(4 * lg + reg) * 64 + ng * 16 + lr] = oacc[ng][reg];
  }
  __syncthreads();

  const float inv = 1.f / (rsbuf[pair * 2][lr] + rsbuf[pair * 2 + 1][lr]);

  // -------------------- Phase 2: pair-leader writes atted -----------------
  if (w == 0) {
    const float* ob = (const float*)(Pw4[wid + 1]);
    float invq[4];
#pragma unroll
    for (int reg = 0; reg < 4; ++reg) invq[reg] = __shfl(inv, 4 * lg + reg);
#pragma unroll
    for (int ng = 0; ng < 4; ++ng) {
#pragma unroll
      for (int reg = 0; reg < 4; ++reg) {
        const int q = q0 + 4 * lg + reg;
        const int d = ng * 16 + lr;
        const float o = oacc[ng][reg] + ob[(4 * lg + reg) * 64 + d];
        atted[((size_t)b * SEQ + q) * HID + h * HD + d] = f2bf(o * invq[reg]);
      }
    }
  }

  // -------------------- Phase 3: att_map burst from registers -------------
  // PLAIN stores: consecutive cg cover adjacent 64B halves of each 128B line,
  // L2 merges them into full lines (no NT partial-line amplification).
  float* arow = att_map + ((size_t)bh * SEQ + q0 + lr) * SEQ + k0w + 4 * lg;
#pragma unroll
  for (int cg = 0; cg < 32; ++cg) {
    const uint2 pr = preg[cg];
    f32x4 wv;
    wv.x = bflo2f(pr.x) * inv;
    wv.y = bfhi2f(pr.x) * inv;
    wv.z = bflo2f(pr.y) * inv;
    wv.w = bfhi2f(pr.y) * inv;
    *reinterpret_cast<f32x4*>(arow + cg * 16) = wv;
  }
}

// ---------------------------------------------------------------------------
extern "C" void kernel_launch(void* const* d_in, const int* in_sizes, int n_in,
                              void* d_out, int out_size, void* d_ws, size_t ws_size,
                              hipStream_t stream) {
  const float* v = (const float*)d_in[0];
  const float* k = (const float*)d_in[1];
  const float* q = (const float*)d_in[2];
  const unsigned char* mask = (const unsigned char*)d_in[3];
  const float* Wv = (const float*)d_in[4];
  const float* bv = (const float*)d_in[5];
  const float* Wk = (const float*)d_in[6];
  const float* bk = (const float*)d_in[7];
  const float* Wq = (const float*)d_in[8];
  const float* bq = (const float*)d_in[9];
  const float* Wm = (const float*)d_in[10];
  const float* bm = (const float*)d_in[11];

  float* out_atted = (float*)d_out;                    // [8,1024,512] f32
  float* out_att = out_atted + (size_t)8 * SEQ * HID;  // [8,8,1024,1024] f32

  const size_t TN = (size_t)8 * SEQ * HID;
  unsigned short* qh = (unsigned short*)d_ws;  // bf16 [B,H,S,D]
  unsigned short* kh = qh + TN;
  unsigned short* vhT = kh + TN;               // bf16 [B,H,D,S]
  unsigned short* aw = vhT + TN;               // bf16 [B,S,H*D]

  proj_qkv<<<dim3(4, 64, 3), 256, 0, stream>>>(q, k, v, Wq, Wk, Wv, bq, bk, bv, qh, kh, vhT);

  attn_fused<<<dim3(2048), 256, 0, stream>>>(qh, kh, vhT, mask, out_att, aw);

  proj_out<<<dim3(4, 64), 256, 0, stream>>>(aw, Wm, bm, out_atted);
}

// Round 15
// 204.770 us; speedup vs baseline: 1.3029x; 1.2540x over previous
//
#include <hip/hip_runtime.h>
#include <cstddef>

// B=8, S=1024, HIDDEN=512, NUM_HEAD=8, HEAD_DIM=64
#define SEQ 1024
#define HID 512
#define NH 8
#define HD 64

typedef __attribute__((ext_vector_type(8))) short bf16x8;
typedef __attribute__((ext_vector_type(4))) float f32x4;

__device__ inline unsigned short f2bf(float f) {
  unsigned u = __builtin_bit_cast(unsigned, f);
  return (unsigned short)((u + 0x7fffu + ((u >> 16) & 1u)) >> 16);
}

// ---------------------------------------------------------------------------
// proj_qkv: one launch for Q,K,V projections (R11 best).
//   z=0 (Q): out [B,H,S,D], scaled 1/8; z=1 (K): [B,H,S,D]; z=2 (V): [B,H,D,S]
// Coalesced epilogue via LDS C-tile.
// ---------------------------------------------------------------------------
__global__ __launch_bounds__(256) void proj_qkv(
    const float* __restrict__ x0, const float* __restrict__ x1, const float* __restrict__ x2,
    const float* __restrict__ w0, const float* __restrict__ w1, const float* __restrict__ w2,
    const float* __restrict__ b0, const float* __restrict__ b1, const float* __restrict__ b2,
    unsigned short* __restrict__ o0, unsigned short* __restrict__ o1,
    unsigned short* __restrict__ o2) {
  __shared__ __align__(16) char smem[32768];
  short* As = (short*)smem;
  short* Bs = As + 128 * 64;
  short* Cs = (short*)smem;

  const int z = blockIdx.z;
  const float* X = z == 0 ? x0 : (z == 1 ? x1 : x2);
  const float* W = z == 0 ? w0 : (z == 1 ? w1 : w2);
  const float* bias = z == 0 ? b0 : (z == 1 ? b1 : b2);
  unsigned short* out = z == 0 ? o0 : (z == 1 ? o1 : o2);
  const float scale = z == 0 ? 0.125f : 1.0f;

  const int t = threadIdx.x;
  const int lane = t & 63, wid = t >> 6;
  const int lg = lane >> 4, lr = lane & 15;
  const int wm = (wid >> 1) * 64, wn = (wid & 1) * 64;
  const int m0 = blockIdx.y * 128, n0 = blockIdx.x * 128;

  f32x4 acc[4][4];
  const f32x4 zf = {0.f, 0.f, 0.f, 0.f};
#pragma unroll
  for (int mg = 0; mg < 4; ++mg)
#pragma unroll
    for (int ng = 0; ng < 4; ++ng) acc[mg][ng] = zf;

  for (int k0 = 0; k0 < 512; k0 += 64) {
    __syncthreads();
#pragma unroll
    for (int i = 0; i < 4; ++i) {
      const int gi = t + i * 256;
      const int r = gi >> 3, g = gi & 7;
      const int dst = r * 64 + ((g ^ (r & 7)) * 8);
      {
        const float* src = X + (size_t)(m0 + r) * 512 + k0 + g * 8;
        const float4 a = *reinterpret_cast<const float4*>(src);
        const float4 b2 = *reinterpret_cast<const float4*>(src + 4);
        union { bf16x8 v; unsigned short u[8]; } p;
        p.u[0] = f2bf(a.x);  p.u[1] = f2bf(a.y);  p.u[2] = f2bf(a.z);  p.u[3] = f2bf(a.w);
        p.u[4] = f2bf(b2.x); p.u[5] = f2bf(b2.y); p.u[6] = f2bf(b2.z); p.u[7] = f2bf(b2.w);
        *reinterpret_cast<bf16x8*>(As + dst) = p.v;
      }
      {
        const float* srcw = W + (size_t)(n0 + r) * 512 + k0 + g * 8;
        const float4 wa = *reinterpret_cast<const float4*>(srcw);
        const float4 wb = *reinterpret_cast<const float4*>(srcw + 4);
        union { bf16x8 v; unsigned short u[8]; } q;
        q.u[0] = f2bf(wa.x); q.u[1] = f2bf(wa.y); q.u[2] = f2bf(wa.z); q.u[3] = f2bf(wa.w);
        q.u[4] = f2bf(wb.x); q.u[5] = f2bf(wb.y); q.u[6] = f2bf(wb.z); q.u[7] = f2bf(wb.w);
        *reinterpret_cast<bf16x8*>(Bs + dst) = q.v;
      }
    }
    __syncthreads();

#pragma unroll
    for (int c = 0; c < 2; ++c) {
      bf16x8 af[4], bfr[4];
#pragma unroll
      for (int mg = 0; mg < 4; ++mg) {
        const int r = wm + mg * 16 + lr;
        af[mg] = *reinterpret_cast<const bf16x8*>(As + r * 64 + (((lg + 4 * c) ^ (r & 7)) * 8));
      }
#pragma unroll
      for (int ng = 0; ng < 4; ++ng) {
        const int r = wn + ng * 16 + lr;
        bfr[ng] = *reinterpret_cast<const bf16x8*>(Bs + r * 64 + (((lg + 4 * c) ^ (r & 7)) * 8));
      }
#pragma unroll
      for (int mg = 0; mg < 4; ++mg)
#pragma unroll
        for (int ng = 0; ng < 4; ++ng)
          acc[mg][ng] =
              __builtin_amdgcn_mfma_f32_16x16x32_bf16(af[mg], bfr[ng], acc[mg][ng], 0, 0, 0);
    }
  }

  float bv[4];
#pragma unroll
  for (int ng = 0; ng < 4; ++ng) bv[ng] = bias[n0 + wn + ng * 16 + lr];

  __syncthreads();

  if (z == 2) {
#pragma unroll
    for (int mg = 0; mg < 4; ++mg) {
#pragma unroll
      for (int reg = 0; reg < 4; ++reg) {
        const int mi = wm + mg * 16 + 4 * lg + reg;
#pragma unroll
        for (int ng = 0; ng < 4; ++ng) {
          const int ni = wn + ng * 16 + lr;
          Cs[ni * 128 + (((mi >> 3) ^ (ni & 15)) * 8) + (mi & 7)] =
              f2bf(acc[mg][ng][reg] + bv[ng]);
        }
      }
    }
  } else {
#pragma unroll
    for (int mg = 0; mg < 4; ++mg) {
#pragma unroll
      for (int reg = 0; reg < 4; ++reg) {
        const int mi = wm + mg * 16 + 4 * lg + reg;
#pragma unroll
        for (int ng = 0; ng < 4; ++ng) {
          const int ni = wn + ng * 16 + lr;
          Cs[mi * 128 + ni] = f2bf((acc[mg][ng][reg] + bv[ng]) * scale);
        }
      }
    }
  }
  __syncthreads();

  const int bb = m0 >> 10;
  const int s_base = m0 & 1023;
  if (z == 2) {
#pragma unroll
    for (int rr = 0; rr < 8; ++rr) {
      const int e = t + rr * 256;
      const int dr = e >> 4;
      const int gm = e & 15;
      const bf16x8 v8 =
          *reinterpret_cast<const bf16x8*>(Cs + dr * 128 + ((gm ^ (dr & 15)) * 8));
      const int h = (n0 + dr) >> 6, d = (n0 + dr) & 63;
      *reinterpret_cast<bf16x8*>(
          out + (((size_t)(bb * NH + h)) * HD + d) * SEQ + s_base + gm * 8) = v8;
    }
  } else {
#pragma unroll
    for (int rr = 0; rr < 8; ++rr) {
      const int e = t + rr * 256;
      const int mi = e >> 4;
      const int gc = e & 15;
      const bf16x8 v8 = *reinterpret_cast<const bf16x8*>(Cs + mi * 128 + gc * 8);
      const int n = n0 + gc * 8;
      const int h = n >> 6, d = n & 63;
      *reinterpret_cast<bf16x8*>(
          out + (((size_t)(bb * NH + h)) * SEQ + s_base + mi) * HD + d) = v8;
    }
  }
}

// ---------------------------------------------------------------------------
// proj_out: atted[8192][512] f32 = X(bf16) @ Wm^T + bm (R11/R12 version)
// ---------------------------------------------------------------------------
__global__ __launch_bounds__(256) void proj_out(const unsigned short* __restrict__ Xb,
                                                const float* __restrict__ W,
                                                const float* __restrict__ bias,
                                                float* __restrict__ outv) {
  __shared__ __align__(16) char smem[32768];
  short* As = (short*)smem;
  short* Bs = As + 128 * 64;
  float* Cs = (float*)smem;  // [64][128] f32 overlay

  const int t = threadIdx.x;
  const int lane = t & 63, wid = t >> 6;
  const int lg = lane >> 4, lr = lane & 15;
  const int wm = (wid >> 1) * 64, wn = (wid & 1) * 64;
  const int m0 = blockIdx.y * 128, n0 = blockIdx.x * 128;

  f32x4 acc[4][4];
  const f32x4 zf = {0.f, 0.f, 0.f, 0.f};
#pragma unroll
  for (int mg = 0; mg < 4; ++mg)
#pragma unroll
    for (int ng = 0; ng < 4; ++ng) acc[mg][ng] = zf;

  for (int k0 = 0; k0 < 512; k0 += 64) {
    __syncthreads();
#pragma unroll
    for (int i = 0; i < 4; ++i) {
      const int gi = t + i * 256;
      const int r = gi >> 3, g = gi & 7;
      const int dst = r * 64 + ((g ^ (r & 7)) * 8);
      *reinterpret_cast<bf16x8*>(As + dst) =
          *reinterpret_cast<const bf16x8*>(Xb + (size_t)(m0 + r) * 512 + k0 + g * 8);
      const float* srcw = W + (size_t)(n0 + r) * 512 + k0 + g * 8;
      const float4 wa = *reinterpret_cast<const float4*>(srcw);
      const float4 wb = *reinterpret_cast<const float4*>(srcw + 4);
      union { bf16x8 v; unsigned short u[8]; } q;
      q.u[0] = f2bf(wa.x); q.u[1] = f2bf(wa.y); q.u[2] = f2bf(wa.z); q.u[3] = f2bf(wa.w);
      q.u[4] = f2bf(wb.x); q.u[5] = f2bf(wb.y); q.u[6] = f2bf(wb.z); q.u[7] = f2bf(wb.w);
      *reinterpret_cast<bf16x8*>(Bs + dst) = q.v;
    }
    __syncthreads();

#pragma unroll
    for (int c = 0; c < 2; ++c) {
      bf16x8 af[4], bfr[4];
#pragma unroll
      for (int mg = 0; mg < 4; ++mg) {
        const int r = wm + mg * 16 + lr;
        af[mg] = *reinterpret_cast<const bf16x8*>(As + r * 64 + (((lg + 4 * c) ^ (r & 7)) * 8));
      }
#pragma unroll
      for (int ng = 0; ng < 4; ++ng) {
        const int r = wn + ng * 16 + lr;
        bfr[ng] = *reinterpret_cast<const bf16x8*>(Bs + r * 64 + (((lg + 4 * c) ^ (r & 7)) * 8));
      }
#pragma unroll
      for (int mg = 0; mg < 4; ++mg)
#pragma unroll
        for (int ng = 0; ng < 4; ++ng)
          acc[mg][ng] =
              __builtin_amdgcn_mfma_f32_16x16x32_bf16(af[mg], bfr[ng], acc[mg][ng], 0, 0, 0);
    }
  }

  float bv[4];
#pragma unroll
  for (int ng = 0; ng < 4; ++ng) bv[ng] = bias[n0 + wn + ng * 16 + lr];

  __syncthreads();

#pragma unroll
  for (int half = 0; half < 2; ++half) {
    if ((wid >> 1) == half) {
#pragma unroll
      for (int mg = 0; mg < 4; ++mg) {
#pragma unroll
        for (int reg = 0; reg < 4; ++reg) {
          const int row = mg * 16 + 4 * lg + reg;  // 0..63 local
#pragma unroll
          for (int ng = 0; ng < 4; ++ng)
            Cs[row * 128 + wn + ng * 16 + lr] = acc[mg][ng][reg] + bv[ng];
        }
      }
    }
    __syncthreads();
#pragma unroll
    for (int rr = 0; rr < 8; ++rr) {
      const int g = t + rr * 256;      // 2048 f32x4 granules
      const int row = g >> 5;          // 0..63
      const int gc = g & 31;
      const f32x4 w4 = *reinterpret_cast<const f32x4*>(Cs + row * 128 + gc * 4);
      *reinterpret_cast<f32x4*>(outv + (size_t)(m0 + half * 64 + row) * 512 + n0 + gc * 4) = w4;
    }
    __syncthreads();
  }
}

// ---------------------------------------------------------------------------
// attn_fused: R7/R11 best attention schedule + T5 s_setprio around MFMA
// clusters. Block = (b,h) x 64 q-rows; 4 waves x 16 q-rows.
// Phase 1 (no global stores): QK swapped (A=K direct global, B=Q regs),
//   exp, rs, P->per-wave LDS, PV MFMA from LDS-staged V^T.
// Phase 2: atted epilogue.
// Phase 3: recompute QK, stream att_map with load-before-store pipelining.
// ---------------------------------------------------------------------------
__global__ __launch_bounds__(256, 4) void attn_fused(const unsigned short* __restrict__ qh,
                                                     const unsigned short* __restrict__ kh,
                                                     const unsigned short* __restrict__ vhT,
                                                     const unsigned char* __restrict__ mask,
                                                     float* __restrict__ att_map,
                                                     unsigned short* __restrict__ atted) {
  __shared__ short Vt[64 * 128];    // V^T tile [d][k], swizzled        16 KB
  __shared__ short Pw4[4][2048];    // per-wave P [16 q][128 k], swz    16 KB
  __shared__ float maskf[1024];     // 0 or -10000                       4 KB

  const int t = threadIdx.x;
  const int lane = t & 63, wid = t >> 6;
  const int lg = lane >> 4, lr = lane & 15;
  const int qt = blockIdx.x & 15;
  const int bh = blockIdx.x >> 4;
  const int b = bh >> 3, h = bh & 7;
  const int q0 = qt * 64 + wid * 16;

  const unsigned short* Qb = qh + ((size_t)bh * SEQ + q0) * HD;
  const unsigned short* Kb = kh + (size_t)bh * SEQ * HD;   // [s][d]
  const unsigned short* Vb = vhT + (size_t)bh * HD * SEQ;  // [d][s]
  const unsigned char* mrow = mask + (size_t)b * SEQ;

#pragma unroll
  for (int i = 0; i < 4; ++i) {
    const int idx = t + i * 256;
    maskf[idx] = mrow[idx] ? -10000.f : 0.f;
  }

  // Q fragments (B-operand: lane lr = q-row; k-granule = lg + 4c). Scaled 1/8.
  bf16x8 qf[2];
#pragma unroll
  for (int c = 0; c < 2; ++c)
    qf[c] = *reinterpret_cast<const bf16x8*>(Qb + (size_t)lr * HD + lg * 8 + 32 * c);

  const f32x4 zf = {0.f, 0.f, 0.f, 0.f};
  f32x4 oacc[4] = {zf, zf, zf, zf};
  float rs = 0.f;
  short* Pw = Pw4[wid];

  // -------------------- Phase 1: compute (no global stores) --------------
  for (int kt = 0; kt < 8; ++kt) {
    __syncthreads();  // Vt reuse guard (first iter: maskf visibility)
#pragma unroll
    for (int i = 0; i < 4; ++i) {
      const int gi = t + i * 256;
      const int d = gi >> 4, g = gi & 15;
      const int slot = (g & 8) | ((g & 7) ^ (d & 7));
      *reinterpret_cast<bf16x8*>(Vt + d * 128 + slot * 8) =
          *reinterpret_cast<const bf16x8*>(Vb + (size_t)d * SEQ + kt * 128 + g * 8);
    }
    __syncthreads();

#pragma unroll
    for (int cg = 0; cg < 8; ++cg) {
      const int r = kt * 128 + cg * 16 + lr;  // key row (A-operand row = lr)
      f32x4 s = zf;
#pragma unroll
      for (int c = 0; c < 2; ++c) {
        const bf16x8 kf =
            *reinterpret_cast<const bf16x8*>(Kb + (size_t)r * HD + (lg + 4 * c) * 8);
        s = __builtin_amdgcn_mfma_f32_16x16x32_bf16(kf, qf[c], s, 0, 0, 0);
      }
      const float4 madd =
          *reinterpret_cast<const float4*>(maskf + kt * 128 + cg * 16 + 4 * lg);
      const float p0 = __expf(s[0] + madd.x);
      const float p1 = __expf(s[1] + madd.y);
      const float p2 = __expf(s[2] + madd.z);
      const float p3 = __expf(s[3] + madd.w);
      rs += (p0 + p1) + (p2 + p3);
      uint2 pr;
      pr.x = (unsigned)f2bf(p0) | ((unsigned)f2bf(p1) << 16);
      pr.y = (unsigned)f2bf(p2) | ((unsigned)f2bf(p3) << 16);
      const int gk = 2 * cg + (lg >> 1);
      *reinterpret_cast<uint2*>(Pw + lr * 128 + ((gk ^ (lr & 7)) * 8) + (lg & 1) * 4) = pr;
    }

    // PV: O[16 q][64 d] += P[16][128] * V[128][64] (unnormalized P)
    __builtin_amdgcn_s_setprio(1);
#pragma unroll
    for (int c = 0; c < 4; ++c) {
      const bf16x8 pa =
          *reinterpret_cast<const bf16x8*>(Pw + lr * 128 + (((lg + 4 * c) ^ (lr & 7)) * 8));
#pragma unroll
      for (int ng = 0; ng < 4; ++ng) {
        const int d = ng * 16 + lr;
        const int gidx = 4 * c + lg;
        const int slot = (gidx & 8) | ((gidx & 7) ^ (d & 7));
        const bf16x8 vf = *reinterpret_cast<const bf16x8*>(Vt + d * 128 + slot * 8);
        oacc[ng] = __builtin_amdgcn_mfma_f32_16x16x32_bf16(pa, vf, oacc[ng], 0, 0, 0);
      }
    }
    __builtin_amdgcn_s_setprio(0);
  }

  rs += __shfl_xor(rs, 16);
  rs += __shfl_xor(rs, 32);
  const float inv = 1.f / rs;

  // -------------------- Phase 2: atted epilogue ---------------------------
  {
    float invq[4];
#pragma unroll
    for (int reg = 0; reg < 4; ++reg) invq[reg] = __shfl(inv, 4 * lg + reg);
#pragma unroll
    for (int ng = 0; ng < 4; ++ng) {
#pragma unroll
      for (int reg = 0; reg < 4; ++reg) {
        const int q = q0 + 4 * lg + reg;
        const int d = ng * 16 + lr;
        atted[((size_t)b * SEQ + q) * HID + h * HD + d] = f2bf(oacc[ng][reg] * invq[reg]);
      }
    }
  }

  // -------------------- Phase 3: pipelined att_map streaming -------------
  float* arow = att_map + ((size_t)bh * SEQ + q0 + lr) * SEQ + 4 * lg;

  bf16x8 kfA[4][2], kfB[4][2];
  auto LD = [&](bf16x8 (&kf)[4][2], int it) {
    const int kt = it >> 1, h4 = (it & 1) * 4;
#pragma unroll
    for (int j = 0; j < 4; ++j) {
      const int r = kt * 128 + (h4 + j) * 16 + lr;
#pragma unroll
      for (int c = 0; c < 2; ++c)
        kf[j][c] =
            *reinterpret_cast<const bf16x8*>(Kb + (size_t)r * HD + (lg + 4 * c) * 8);
    }
  };
  auto CS = [&](bf16x8 (&kf)[4][2], int it) {
    const int kt = it >> 1, h4 = (it & 1) * 4;
    __builtin_amdgcn_s_setprio(1);
#pragma unroll
    for (int j = 0; j < 4; ++j) {
      f32x4 s = zf;
      s = __builtin_amdgcn_mfma_f32_16x16x32_bf16(kf[j][0], qf[0], s, 0, 0, 0);
      s = __builtin_amdgcn_mfma_f32_16x16x32_bf16(kf[j][1], qf[1], s, 0, 0, 0);
      const int kbase = kt * 128 + (h4 + j) * 16;
      const float4 madd = *reinterpret_cast<const float4*>(maskf + kbase + 4 * lg);
      f32x4 w;
      w.x = __expf(s[0] + madd.x) * inv;
      w.y = __expf(s[1] + madd.y) * inv;
      w.z = __expf(s[2] + madd.z) * inv;
      w.w = __expf(s[3] + madd.w) * inv;
      __builtin_nontemporal_store(w, reinterpret_cast<f32x4*>(arow + kbase));
    }
    __builtin_amdgcn_s_setprio(0);
  };

  LD(kfA, 0);
#pragma unroll
  for (int ip = 0; ip < 8; ++ip) {
    LD(kfB, ip * 2 + 1);   // issue next loads BEFORE current stores
    CS(kfA, ip * 2);
    if (ip * 2 + 2 < 16) LD(kfA, ip * 2 + 2);
    CS(kfB, ip * 2 + 1);
  }
}

// ---------------------------------------------------------------------------
extern "C" void kernel_launch(void* const* d_in, const int* in_sizes, int n_in,
                              void* d_out, int out_size, void* d_ws, size_t ws_size,
                              hipStream_t stream) {
  const float* v = (const float*)d_in[0];
  const float* k = (const float*)d_in[1];
  const float* q = (const float*)d_in[2];
  const unsigned char* mask = (const unsigned char*)d_in[3];
  const float* Wv = (const float*)d_in[4];
  const float* bv = (const float*)d_in[5];
  const float* Wk = (const float*)d_in[6];
  const float* bk = (const float*)d_in[7];
  const float* Wq = (const float*)d_in[8];
  const float* bq = (const float*)d_in[9];
  const float* Wm = (const float*)d_in[10];
  const float* bm = (const float*)d_in[11];

  float* out_atted = (float*)d_out;                    // [8,1024,512] f32
  float* out_att = out_atted + (size_t)8 * SEQ * HID;  // [8,8,1024,1024] f32

  const size_t TN = (size_t)8 * SEQ * HID;
  unsigned short* qh = (unsigned short*)d_ws;  // bf16 [B,H,S,D]
  unsigned short* kh = qh + TN;
  unsigned short* vhT = kh + TN;               // bf16 [B,H,D,S]
  unsigned short* aw = vhT + TN;               // bf16 [B,S,H*D]

  proj_qkv<<<dim3(4, 64, 3), 256, 0, stream>>>(q, k, v, Wq, Wk, Wv, bq, bk, bv, qh, kh, vhT);

  attn_fused<<<dim3(1024), 256, 0, stream>>>(qh, kh, vhT, mask, out_att, aw);

  proj_out<<<dim3(4, 64), 256, 0, stream>>>(aw, Wm, bm, out_atted);
}

// Round 16
// 203.069 us; speedup vs baseline: 1.3138x; 1.0084x over previous
//
#include <hip/hip_runtime.h>
#include <cstddef>

// B=8, S=1024, HIDDEN=512, NUM_HEAD=8, HEAD_DIM=64
#define SEQ 1024
#define HID 512
#define NH 8
#define HD 64

typedef __attribute__((ext_vector_type(8))) short bf16x8;
typedef __attribute__((ext_vector_type(4))) float f32x4;

__device__ inline unsigned short f2bf(float f) {
  unsigned u = __builtin_bit_cast(unsigned, f);
  return (unsigned short)((u + 0x7fffu + ((u >> 16) & 1u)) >> 16);
}

// ---------------------------------------------------------------------------
// proj_qkv: one launch for Q,K,V projections (measured-best R11 version).
//   z=0 (Q): out [B,H,S,D], scaled 1/8; z=1 (K): [B,H,S,D]; z=2 (V): [B,H,D,S]
// Coalesced epilogue via LDS C-tile (bf16x8 stores: 128B/256B segments).
// ---------------------------------------------------------------------------
__global__ __launch_bounds__(256) void proj_qkv(
    const float* __restrict__ x0, const float* __restrict__ x1, const float* __restrict__ x2,
    const float* __restrict__ w0, const float* __restrict__ w1, const float* __restrict__ w2,
    const float* __restrict__ b0, const float* __restrict__ b1, const float* __restrict__ b2,
    unsigned short* __restrict__ o0, unsigned short* __restrict__ o1,
    unsigned short* __restrict__ o2) {
  __shared__ __align__(16) char smem[32768];
  short* As = (short*)smem;        // [128][64] bf16, swizzled (main loop)
  short* Bs = As + 128 * 64;       // [128][64]
  short* Cs = (short*)smem;        // [128][128] bf16 (epilogue overlay)

  const int z = blockIdx.z;
  const float* X = z == 0 ? x0 : (z == 1 ? x1 : x2);
  const float* W = z == 0 ? w0 : (z == 1 ? w1 : w2);
  const float* bias = z == 0 ? b0 : (z == 1 ? b1 : b2);
  unsigned short* out = z == 0 ? o0 : (z == 1 ? o1 : o2);
  const float scale = z == 0 ? 0.125f : 1.0f;

  const int t = threadIdx.x;
  const int lane = t & 63, wid = t >> 6;
  const int lg = lane >> 4, lr = lane & 15;
  const int wm = (wid >> 1) * 64, wn = (wid & 1) * 64;
  const int m0 = blockIdx.y * 128, n0 = blockIdx.x * 128;

  f32x4 acc[4][4];
  const f32x4 zf = {0.f, 0.f, 0.f, 0.f};
#pragma unroll
  for (int mg = 0; mg < 4; ++mg)
#pragma unroll
    for (int ng = 0; ng < 4; ++ng) acc[mg][ng] = zf;

  for (int k0 = 0; k0 < 512; k0 += 64) {
    __syncthreads();
#pragma unroll
    for (int i = 0; i < 4; ++i) {
      const int gi = t + i * 256;
      const int r = gi >> 3, g = gi & 7;
      const int dst = r * 64 + ((g ^ (r & 7)) * 8);
      {
        const float* src = X + (size_t)(m0 + r) * 512 + k0 + g * 8;
        const float4 a = *reinterpret_cast<const float4*>(src);
        const float4 b2 = *reinterpret_cast<const float4*>(src + 4);
        union { bf16x8 v; unsigned short u[8]; } p;
        p.u[0] = f2bf(a.x);  p.u[1] = f2bf(a.y);  p.u[2] = f2bf(a.z);  p.u[3] = f2bf(a.w);
        p.u[4] = f2bf(b2.x); p.u[5] = f2bf(b2.y); p.u[6] = f2bf(b2.z); p.u[7] = f2bf(b2.w);
        *reinterpret_cast<bf16x8*>(As + dst) = p.v;
      }
      {
        const float* srcw = W + (size_t)(n0 + r) * 512 + k0 + g * 8;
        const float4 wa = *reinterpret_cast<const float4*>(srcw);
        const float4 wb = *reinterpret_cast<const float4*>(srcw + 4);
        union { bf16x8 v; unsigned short u[8]; } q;
        q.u[0] = f2bf(wa.x); q.u[1] = f2bf(wa.y); q.u[2] = f2bf(wa.z); q.u[3] = f2bf(wa.w);
        q.u[4] = f2bf(wb.x); q.u[5] = f2bf(wb.y); q.u[6] = f2bf(wb.z); q.u[7] = f2bf(wb.w);
        *reinterpret_cast<bf16x8*>(Bs + dst) = q.v;
      }
    }
    __syncthreads();

#pragma unroll
    for (int c = 0; c < 2; ++c) {
      bf16x8 af[4], bfr[4];
#pragma unroll
      for (int mg = 0; mg < 4; ++mg) {
        const int r = wm + mg * 16 + lr;
        af[mg] = *reinterpret_cast<const bf16x8*>(As + r * 64 + (((lg + 4 * c) ^ (r & 7)) * 8));
      }
#pragma unroll
      for (int ng = 0; ng < 4; ++ng) {
        const int r = wn + ng * 16 + lr;
        bfr[ng] = *reinterpret_cast<const bf16x8*>(Bs + r * 64 + (((lg + 4 * c) ^ (r & 7)) * 8));
      }
#pragma unroll
      for (int mg = 0; mg < 4; ++mg)
#pragma unroll
        for (int ng = 0; ng < 4; ++ng)
          acc[mg][ng] =
              __builtin_amdgcn_mfma_f32_16x16x32_bf16(af[mg], bfr[ng], acc[mg][ng], 0, 0, 0);
    }
  }

  float bv[4];
#pragma unroll
  for (int ng = 0; ng < 4; ++ng) bv[ng] = bias[n0 + wn + ng * 16 + lr];

  __syncthreads();  // done reading As/Bs; Cs overlays them

  if (z == 2) {
    // transposed + granule-swizzled: (mi,ni) -> Cs[ni][granule (mi>>3)^(ni&15)]
#pragma unroll
    for (int mg = 0; mg < 4; ++mg) {
#pragma unroll
      for (int reg = 0; reg < 4; ++reg) {
        const int mi = wm + mg * 16 + 4 * lg + reg;
#pragma unroll
        for (int ng = 0; ng < 4; ++ng) {
          const int ni = wn + ng * 16 + lr;
          Cs[ni * 128 + (((mi >> 3) ^ (ni & 15)) * 8) + (mi & 7)] =
              f2bf(acc[mg][ng][reg] + bv[ng]);
        }
      }
    }
  } else {
#pragma unroll
    for (int mg = 0; mg < 4; ++mg) {
#pragma unroll
      for (int reg = 0; reg < 4; ++reg) {
        const int mi = wm + mg * 16 + 4 * lg + reg;
#pragma unroll
        for (int ng = 0; ng < 4; ++ng) {
          const int ni = wn + ng * 16 + lr;
          Cs[mi * 128 + ni] = f2bf((acc[mg][ng][reg] + bv[ng]) * scale);
        }
      }
    }
  }
  __syncthreads();

  // coalesced flush: 2048 granules of 8 bf16, 8 rounds x 256 threads
  const int bb = m0 >> 10;
  const int s_base = m0 & 1023;
  if (z == 2) {
#pragma unroll
    for (int rr = 0; rr < 8; ++rr) {
      const int e = t + rr * 256;
      const int dr = e >> 4;   // 0..127 (= ni)
      const int gm = e & 15;   // s-granule
      const bf16x8 v8 =
          *reinterpret_cast<const bf16x8*>(Cs + dr * 128 + ((gm ^ (dr & 15)) * 8));
      const int h = (n0 + dr) >> 6, d = (n0 + dr) & 63;
      *reinterpret_cast<bf16x8*>(
          out + (((size_t)(bb * NH + h)) * HD + d) * SEQ + s_base + gm * 8) = v8;
    }
  } else {
#pragma unroll
    for (int rr = 0; rr < 8; ++rr) {
      const int e = t + rr * 256;
      const int mi = e >> 4;   // 0..127 (s-row)
      const int gc = e & 15;   // n-granule
      const bf16x8 v8 = *reinterpret_cast<const bf16x8*>(Cs + mi * 128 + gc * 8);
      const int n = n0 + gc * 8;
      const int h = n >> 6, d = n & 63;
      *reinterpret_cast<bf16x8*>(
          out + (((size_t)(bb * NH + h)) * SEQ + s_base + mi) * HD + d) = v8;
    }
  }
}

// ---------------------------------------------------------------------------
// proj_out: atted[8192][512] f32 = X(bf16) @ Wm^T + bm  (R11 version)
// ---------------------------------------------------------------------------
__global__ __launch_bounds__(256) void proj_out(const unsigned short* __restrict__ Xb,
                                                const float* __restrict__ W,
                                                const float* __restrict__ bias,
                                                float* __restrict__ outv) {
  __shared__ short As[128 * 64];
  __shared__ short Bs[128 * 64];

  const int t = threadIdx.x;
  const int lane = t & 63, wid = t >> 6;
  const int lg = lane >> 4, lr = lane & 15;
  const int wm = (wid >> 1) * 64, wn = (wid & 1) * 64;
  const int m0 = blockIdx.y * 128, n0 = blockIdx.x * 128;

  f32x4 acc[4][4];
  const f32x4 zf = {0.f, 0.f, 0.f, 0.f};
#pragma unroll
  for (int mg = 0; mg < 4; ++mg)
#pragma unroll
    for (int ng = 0; ng < 4; ++ng) acc[mg][ng] = zf;

  for (int k0 = 0; k0 < 512; k0 += 64) {
    __syncthreads();
#pragma unroll
    for (int i = 0; i < 4; ++i) {
      const int gi = t + i * 256;
      const int r = gi >> 3, g = gi & 7;
      const int dst = r * 64 + ((g ^ (r & 7)) * 8);
      *reinterpret_cast<bf16x8*>(As + dst) =
          *reinterpret_cast<const bf16x8*>(Xb + (size_t)(m0 + r) * 512 + k0 + g * 8);
      const float* srcw = W + (size_t)(n0 + r) * 512 + k0 + g * 8;
      const float4 wa = *reinterpret_cast<const float4*>(srcw);
      const float4 wb = *reinterpret_cast<const float4*>(srcw + 4);
      union { bf16x8 v; unsigned short u[8]; } q;
      q.u[0] = f2bf(wa.x); q.u[1] = f2bf(wa.y); q.u[2] = f2bf(wa.z); q.u[3] = f2bf(wa.w);
      q.u[4] = f2bf(wb.x); q.u[5] = f2bf(wb.y); q.u[6] = f2bf(wb.z); q.u[7] = f2bf(wb.w);
      *reinterpret_cast<bf16x8*>(Bs + dst) = q.v;
    }
    __syncthreads();

#pragma unroll
    for (int c = 0; c < 2; ++c) {
      bf16x8 af[4], bfr[4];
#pragma unroll
      for (int mg = 0; mg < 4; ++mg) {
        const int r = wm + mg * 16 + lr;
        af[mg] = *reinterpret_cast<const bf16x8*>(As + r * 64 + (((lg + 4 * c) ^ (r & 7)) * 8));
      }
#pragma unroll
      for (int ng = 0; ng < 4; ++ng) {
        const int r = wn + ng * 16 + lr;
        bfr[ng] = *reinterpret_cast<const bf16x8*>(Bs + r * 64 + (((lg + 4 * c) ^ (r & 7)) * 8));
      }
#pragma unroll
      for (int mg = 0; mg < 4; ++mg)
#pragma unroll
        for (int ng = 0; ng < 4; ++ng)
          acc[mg][ng] =
              __builtin_amdgcn_mfma_f32_16x16x32_bf16(af[mg], bfr[ng], acc[mg][ng], 0, 0, 0);
    }
  }

  float bv[4];
#pragma unroll
  for (int ng = 0; ng < 4; ++ng) bv[ng] = bias[n0 + wn + ng * 16 + lr];

#pragma unroll
  for (int mg = 0; mg < 4; ++mg) {
#pragma unroll
    for (int reg = 0; reg < 4; ++reg) {
      const int m = m0 + wm + mg * 16 + 4 * lg + reg;
#pragma unroll
      for (int ng = 0; ng < 4; ++ng) {
        const int n = n0 + wn + ng * 16 + lr;
        __builtin_nontemporal_store(acc[mg][ng][reg] + bv[ng], outv + (size_t)m * 512 + n);
      }
    }
  }
}

// ---------------------------------------------------------------------------
// attn_fused: the measured-best (R7/R11) attention schedule.
// Block = (b,h) x 64 q-rows; 4 waves x 16 q-rows.
// Phase 1 (compute, NO global stores): QK swapped (A=K direct global, B=Q
//   regs), exp, rs, P->per-wave LDS, PV MFMA from LDS-staged V^T.
// Phase 2: atted epilogue.
// Phase 3: recompute QK, stream att_map with load-before-store pipelining.
// ---------------------------------------------------------------------------
__global__ __launch_bounds__(256, 4) void attn_fused(const unsigned short* __restrict__ qh,
                                                     const unsigned short* __restrict__ kh,
                                                     const unsigned short* __restrict__ vhT,
                                                     const unsigned char* __restrict__ mask,
                                                     float* __restrict__ att_map,
                                                     unsigned short* __restrict__ atted) {
  __shared__ short Vt[64 * 128];    // V^T tile [d][k], swizzled        16 KB
  __shared__ short Pw4[4][2048];    // per-wave P [16 q][128 k], swz    16 KB
  __shared__ float maskf[1024];     // 0 or -10000                       4 KB

  const int t = threadIdx.x;
  const int lane = t & 63, wid = t >> 6;
  const int lg = lane >> 4, lr = lane & 15;
  const int qt = blockIdx.x & 15;
  const int bh = blockIdx.x >> 4;
  const int b = bh >> 3, h = bh & 7;
  const int q0 = qt * 64 + wid * 16;

  const unsigned short* Qb = qh + ((size_t)bh * SEQ + q0) * HD;
  const unsigned short* Kb = kh + (size_t)bh * SEQ * HD;   // [s][d]
  const unsigned short* Vb = vhT + (size_t)bh * HD * SEQ;  // [d][s]
  const unsigned char* mrow = mask + (size_t)b * SEQ;

#pragma unroll
  for (int i = 0; i < 4; ++i) {
    const int idx = t + i * 256;
    maskf[idx] = mrow[idx] ? -10000.f : 0.f;
  }

  // Q fragments (B-operand: lane lr = q-row; k-granule = lg + 4c). Scaled 1/8.
  bf16x8 qf[2];
#pragma unroll
  for (int c = 0; c < 2; ++c)
    qf[c] = *reinterpret_cast<const bf16x8*>(Qb + (size_t)lr * HD + lg * 8 + 32 * c);

  const f32x4 zf = {0.f, 0.f, 0.f, 0.f};
  f32x4 oacc[4] = {zf, zf, zf, zf};
  float rs = 0.f;
  short* Pw = Pw4[wid];

  // -------------------- Phase 1: compute (no global stores) --------------
  for (int kt = 0; kt < 8; ++kt) {
    __syncthreads();  // Vt reuse guard (first iter: maskf visibility)
#pragma unroll
    for (int i = 0; i < 4; ++i) {
      const int gi = t + i * 256;
      const int d = gi >> 4, g = gi & 15;
      const int slot = (g & 8) | ((g & 7) ^ (d & 7));
      *reinterpret_cast<bf16x8*>(Vt + d * 128 + slot * 8) =
          *reinterpret_cast<const bf16x8*>(Vb + (size_t)d * SEQ + kt * 128 + g * 8);
    }
    __syncthreads();

#pragma unroll
    for (int cg = 0; cg < 8; ++cg) {
      const int r = kt * 128 + cg * 16 + lr;  // key row (A-operand row = lr)
      f32x4 s = zf;
#pragma unroll
      for (int c = 0; c < 2; ++c) {
        const bf16x8 kf =
            *reinterpret_cast<const bf16x8*>(Kb + (size_t)r * HD + (lg + 4 * c) * 8);
        s = __builtin_amdgcn_mfma_f32_16x16x32_bf16(kf, qf[c], s, 0, 0, 0);
      }
      const float4 madd =
          *reinterpret_cast<const float4*>(maskf + kt * 128 + cg * 16 + 4 * lg);
      const float p0 = __expf(s[0] + madd.x);
      const float p1 = __expf(s[1] + madd.y);
      const float p2 = __expf(s[2] + madd.z);
      const float p3 = __expf(s[3] + madd.w);
      rs += (p0 + p1) + (p2 + p3);
      uint2 pr;
      pr.x = (unsigned)f2bf(p0) | ((unsigned)f2bf(p1) << 16);
      pr.y = (unsigned)f2bf(p2) | ((unsigned)f2bf(p3) << 16);
      const int gk = 2 * cg + (lg >> 1);
      *reinterpret_cast<uint2*>(Pw + lr * 128 + ((gk ^ (lr & 7)) * 8) + (lg & 1) * 4) = pr;
    }

    // PV: O[16 q][64 d] += P[16][128] * V[128][64] (unnormalized P)
#pragma unroll
    for (int c = 0; c < 4; ++c) {
      const bf16x8 pa =
          *reinterpret_cast<const bf16x8*>(Pw + lr * 128 + (((lg + 4 * c) ^ (lr & 7)) * 8));
#pragma unroll
      for (int ng = 0; ng < 4; ++ng) {
        const int d = ng * 16 + lr;
        const int gidx = 4 * c + lg;
        const int slot = (gidx & 8) | ((gidx & 7) ^ (d & 7));
        const bf16x8 vf = *reinterpret_cast<const bf16x8*>(Vt + d * 128 + slot * 8);
        oacc[ng] = __builtin_amdgcn_mfma_f32_16x16x32_bf16(pa, vf, oacc[ng], 0, 0, 0);
      }
    }
  }

  rs += __shfl_xor(rs, 16);
  rs += __shfl_xor(rs, 32);
  const float inv = 1.f / rs;

  // -------------------- Phase 2: atted epilogue ---------------------------
  {
    float invq[4];
#pragma unroll
    for (int reg = 0; reg < 4; ++reg) invq[reg] = __shfl(inv, 4 * lg + reg);
#pragma unroll
    for (int ng = 0; ng < 4; ++ng) {
#pragma unroll
      for (int reg = 0; reg < 4; ++reg) {
        const int q = q0 + 4 * lg + reg;
        const int d = ng * 16 + lr;
        atted[((size_t)b * SEQ + q) * HID + h * HD + d] = f2bf(oacc[ng][reg] * invq[reg]);
      }
    }
  }

  // -------------------- Phase 3: pipelined att_map streaming -------------
  float* arow = att_map + ((size_t)bh * SEQ + q0 + lr) * SEQ + 4 * lg;

  bf16x8 kfA[4][2], kfB[4][2];
  auto LD = [&](bf16x8 (&kf)[4][2], int it) {
    const int kt = it >> 1, h4 = (it & 1) * 4;
#pragma unroll
    for (int j = 0; j < 4; ++j) {
      const int r = kt * 128 + (h4 + j) * 16 + lr;
#pragma unroll
      for (int c = 0; c < 2; ++c)
        kf[j][c] =
            *reinterpret_cast<const bf16x8*>(Kb + (size_t)r * HD + (lg + 4 * c) * 8);
    }
  };
  auto CS = [&](bf16x8 (&kf)[4][2], int it) {
    const int kt = it >> 1, h4 = (it & 1) * 4;
#pragma unroll
    for (int j = 0; j < 4; ++j) {
      f32x4 s = zf;
      s = __builtin_amdgcn_mfma_f32_16x16x32_bf16(kf[j][0], qf[0], s, 0, 0, 0);
      s = __builtin_amdgcn_mfma_f32_16x16x32_bf16(kf[j][1], qf[1], s, 0, 0, 0);
      const int kbase = kt * 128 + (h4 + j) * 16;
      const float4 madd = *reinterpret_cast<const float4*>(maskf + kbase + 4 * lg);
      f32x4 w;
      w.x = __expf(s[0] + madd.x) * inv;
      w.y = __expf(s[1] + madd.y) * inv;
      w.z = __expf(s[2] + madd.z) * inv;
      w.w = __expf(s[3] + madd.w) * inv;
      __builtin_nontemporal_store(w, reinterpret_cast<f32x4*>(arow + kbase));
    }
  };

  LD(kfA, 0);
#pragma unroll
  for (int ip = 0; ip < 8; ++ip) {
    LD(kfB, ip * 2 + 1);   // issue next loads BEFORE current stores
    CS(kfA, ip * 2);
    if (ip * 2 + 2 < 16) LD(kfA, ip * 2 + 2);
    CS(kfB, ip * 2 + 1);
  }
}

// ---------------------------------------------------------------------------
extern "C" void kernel_launch(void* const* d_in, const int* in_sizes, int n_in,
                              void* d_out, int out_size, void* d_ws, size_t ws_size,
                              hipStream_t stream) {
  const float* v = (const float*)d_in[0];
  const float* k = (const float*)d_in[1];
  const float* q = (const float*)d_in[2];
  const unsigned char* mask = (const unsigned char*)d_in[3];
  const float* Wv = (const float*)d_in[4];
  const float* bv = (const float*)d_in[5];
  const float* Wk = (const float*)d_in[6];
  const float* bk = (const float*)d_in[7];
  const float* Wq = (const float*)d_in[8];
  const float* bq = (const float*)d_in[9];
  const float* Wm = (const float*)d_in[10];
  const float* bm = (const float*)d_in[11];

  float* out_atted = (float*)d_out;                    // [8,1024,512] f32
  float* out_att = out_atted + (size_t)8 * SEQ * HID;  // [8,8,1024,1024] f32

  const size_t TN = (size_t)8 * SEQ * HID;
  unsigned short* qh = (unsigned short*)d_ws;  // bf16 [B,H,S,D]
  unsigned short* kh = qh + TN;
  unsigned short* vhT = kh + TN;               // bf16 [B,H,D,S]
  unsigned short* aw = vhT + TN;               // bf16 [B,S,H*D]

  proj_qkv<<<dim3(4, 64, 3), 256, 0, stream>>>(q, k, v, Wq, Wk, Wv, bq, bk, bv, qh, kh, vhT);

  attn_fused<<<dim3(1024), 256, 0, stream>>>(qh, kh, vhT, mask, out_att, aw);

  proj_out<<<dim3(4, 64), 256, 0, stream>>>(aw, Wm, bm, out_atted);
}